// Round 3
// baseline (110.306 us; speedup 1.0000x reference)
//
#include <hip/hip_runtime.h>
#include <hip/hip_bf16.h>

#define LOG2PI_F 1.8378770664093453f
#define LOG2E_F  1.4426950408889634f
#define LN2_F    0.6931471805599453f

// ws layout:
//   Ac[128][256] f32  @ 0        (128 KB)  log2e*(logw - .5(log2pi+lv) - .5 e^-lv mu^2)
//   Bc[128][256] f32  @ 128 KB   (128 KB)  log2e*(e^-lv mu)
//   Cc[128][256] f32  @ 256 KB   (128 KB)  log2e*(-.5 e^-lv)
//   xy[4096][128] float2 @ 384 KB (4 MB)   (Ez, Ez2)

// Heterogeneous: blocks 0..127 build coefficients (d = blockIdx);
// blocks 128..639 reduce z over MC with full-row float4 coalescing.
__global__ __launch_bounds__(256) void prep_kernel(
    const float* __restrict__ z, const float* __restrict__ means,
    const float* __restrict__ log_vars, const float* __restrict__ w,
    float* __restrict__ Ac, float* __restrict__ Bc, float* __restrict__ Cc,
    float2* __restrict__ xy)
{
    const int t = threadIdx.x;
    if (blockIdx.x < 128) {
        __shared__ float red[256];
        const int d = blockIdx.x;
        // log_softmax over K=256 (redundant per block, cheap)
        float wv = w[t];
        red[t] = wv; __syncthreads();
        for (int off = 128; off > 0; off >>= 1) {
            if (t < off) red[t] = fmaxf(red[t], red[t + off]);
            __syncthreads();
        }
        float m = red[0]; __syncthreads();
        red[t] = expf(wv - m); __syncthreads();
        for (int off = 128; off > 0; off >>= 1) {
            if (t < off) red[t] += red[t + off];
            __syncthreads();
        }
        float logw = wv - m - logf(red[0]);

        const int idx = t * 128 + d;       // means/log_vars are [K][D]
        float mu = means[idx];
        float lv = log_vars[idx];
        float p  = expf(-lv);
        Ac[(d << 8) + t] = (-0.5f * (LOG2PI_F + lv) - 0.5f * p * mu * mu + logw) * LOG2E_F;
        Bc[(d << 8) + t] = p * mu * LOG2E_F;
        Cc[(d << 8) + t] = -0.5f * p * LOG2E_F;
    } else {
        // Ez/Ez2: thread owns (b, 4 consecutive d); float4 loads, coalesced.
        const int gid = (blockIdx.x - 128) * 256 + t;   // 0..131071
        const int b  = gid >> 5;
        const int d4 = gid & 31;
        const float* zp = z + ((size_t)b << 7) + (d4 << 2);
        float s10 = 0.f, s11 = 0.f, s12 = 0.f, s13 = 0.f;
        float s20 = 0.f, s21 = 0.f, s22 = 0.f, s23 = 0.f;
        #pragma unroll
        for (int mc = 0; mc < 16; ++mc) {
            float4 v = *(const float4*)(zp + (size_t)mc * 524288);
            s10 += v.x; s20 = fmaf(v.x, v.x, s20);
            s11 += v.y; s21 = fmaf(v.y, v.y, s21);
            s12 += v.z; s22 = fmaf(v.z, v.z, s22);
            s13 += v.w; s23 = fmaf(v.w, v.w, s23);
        }
        float4* op = (float4*)xy + ((size_t)b << 6) + (d4 << 1);
        op[0] = make_float4(s10 * 0.0625f, s20 * 0.0625f, s11 * 0.0625f, s21 * 0.0625f);
        op[1] = make_float4(s12 * 0.0625f, s22 * 0.0625f, s13 * 0.0625f, s23 * 0.0625f);
    }
}

// 1024 blocks x 128 thr. Wave owns one d (uniform); lane l holds coefficients
// for k in {4l..4l+3} in 12 VGPRs; k-loop broadcasts them via v_readlane
// (pure VALU -- zero LDS, zero inner-loop memory). Lane owns 4 b values.
__global__ __launch_bounds__(128) void lse_kernel(
    const float* __restrict__ Ac, const float* __restrict__ Bc,
    const float* __restrict__ Cc, const float2* __restrict__ xy,
    float* __restrict__ out)
{
    const int t  = threadIdx.x;
    const int l  = t & 63;
    const int d  = ((blockIdx.x & 63) << 1) + (t >> 6);  // wave-uniform
    const int b0 = (blockIdx.x >> 6) << 8;               // 16 chunks x 256 b

    const int ci = (d << 8) + (l << 2);
    const float4 cA = *(const float4*)&Ac[ci];
    const float4 cB = *(const float4*)&Bc[ci];
    const float4 cC = *(const float4*)&Cc[ci];

    float x0, x1, x2, x3, y0, y1, y2, y3;
    { float2 v = xy[((size_t)(b0 + l)       << 7) + d]; x0 = v.x; y0 = v.y; }
    { float2 v = xy[((size_t)(b0 + l +  64) << 7) + d]; x1 = v.x; y1 = v.y; }
    { float2 v = xy[((size_t)(b0 + l + 128) << 7) + d]; x2 = v.x; y2 = v.y; }
    { float2 v = xy[((size_t)(b0 + l + 192) << 7) + d]; x3 = v.x; y3 = v.y; }

    float a0 = 0.f, a1 = 0.f, a2 = 0.f, a3 = 0.f;

    #define RL(v) __int_as_float(__builtin_amdgcn_readlane(__float_as_int(v), k0))
    #define BODY(F)                                                          \
    {                                                                        \
        float sa = RL(cA.F), sb = RL(cB.F), sc = RL(cC.F);                   \
        a0 += __builtin_amdgcn_exp2f(fmaf(sc, y0, fmaf(sb, x0, sa)));        \
        a1 += __builtin_amdgcn_exp2f(fmaf(sc, y1, fmaf(sb, x1, sa)));        \
        a2 += __builtin_amdgcn_exp2f(fmaf(sc, y2, fmaf(sb, x2, sa)));        \
        a3 += __builtin_amdgcn_exp2f(fmaf(sc, y3, fmaf(sb, x3, sa)));        \
    }
    #pragma unroll 4
    for (int k0 = 0; k0 < 64; ++k0) {
        BODY(x) BODY(y) BODY(z) BODY(w)
    }
    #undef BODY
    #undef RL

    out[(size_t)(b0 + l)       * 128 + d] = LN2_F * __builtin_amdgcn_logf(a0);
    out[(size_t)(b0 + l +  64) * 128 + d] = LN2_F * __builtin_amdgcn_logf(a1);
    out[(size_t)(b0 + l + 128) * 128 + d] = LN2_F * __builtin_amdgcn_logf(a2);
    out[(size_t)(b0 + l + 192) * 128 + d] = LN2_F * __builtin_amdgcn_logf(a3);
}

extern "C" void kernel_launch(void* const* d_in, const int* in_sizes, int n_in,
                              void* d_out, int out_size, void* d_ws, size_t ws_size,
                              hipStream_t stream) {
    const float* z        = (const float*)d_in[0];
    const float* means    = (const float*)d_in[1];
    const float* log_vars = (const float*)d_in[2];
    const float* w        = (const float*)d_in[3];
    float* out = (float*)d_out;

    char* ws = (char*)d_ws;
    float*  Ac = (float*)(ws);
    float*  Bc = (float*)(ws + (128 << 10));
    float*  Cc = (float*)(ws + (256 << 10));
    float2* xy = (float2*)(ws + (384 << 10));

    prep_kernel<<<640, 256, 0, stream>>>(z, means, log_vars, w, Ac, Bc, Cc, xy);
    lse_kernel<<<1024, 128, 0, stream>>>(Ac, Bc, Cc, xy, out);
}

// Round 5
// 104.776 us; speedup vs baseline: 1.0528x; 1.0528x over previous
//
#include <hip/hip_runtime.h>
#include <hip/hip_bf16.h>

#define LOG2PI_F 1.8378770664093453f
#define LOG2E_F  1.4426950408889634f
#define LN2_F    0.6931471805599453f

// ws layout:
//   Ac[128][256] f32   @ 0        (128 KB)  log2e*(logw -.5(log2pi+lv) -.5 e^-lv mu^2)
//   Bc[128][256] f32   @ 128 KB   (128 KB)  log2e*(e^-lv mu)
//   Cc[128][256] f32   @ 256 KB   (128 KB)  log2e*(-.5 e^-lv)
//   xy_t[128][4096] float2 @ 384 KB (4 MB)  TRANSPOSED (Ez,Ez2): b contiguous!

// Heterogeneous: blocks 0..127 build coefficients (d = blockIdx);
// blocks 128..639 reduce z over MC (8 b each) + LDS-transpose -> xy_t.
__global__ __launch_bounds__(256) void prep_kernel(
    const float* __restrict__ z, const float* __restrict__ means,
    const float* __restrict__ log_vars, const float* __restrict__ w,
    float* __restrict__ Ac, float* __restrict__ Bc, float* __restrict__ Cc,
    float2* __restrict__ xyt)
{
    const int t = threadIdx.x;
    if (blockIdx.x < 128) {
        __shared__ float red[256];
        const int d = blockIdx.x;
        float wv = w[t];
        red[t] = wv; __syncthreads();
        for (int off = 128; off > 0; off >>= 1) {
            if (t < off) red[t] = fmaxf(red[t], red[t + off]);
            __syncthreads();
        }
        float m = red[0]; __syncthreads();
        red[t] = expf(wv - m); __syncthreads();
        for (int off = 128; off > 0; off >>= 1) {
            if (t < off) red[t] += red[t + off];
            __syncthreads();
        }
        float logw = wv - m - logf(red[0]);

        const int idx = t * 128 + d;       // means/log_vars are [K][D]
        float mu = means[idx];
        float lv = log_vars[idx];
        float p  = expf(-lv);
        Ac[(d << 8) + t] = (-0.5f * (LOG2PI_F + lv) - 0.5f * p * mu * mu + logw) * LOG2E_F;
        Bc[(d << 8) + t] = p * mu * LOG2E_F;
        Cc[(d << 8) + t] = -0.5f * p * LOG2E_F;
    } else {
        // ---- z reduction: 8 b per block, perfectly coalesced float4 rows ----
        __shared__ float2 tr[128][8];      // [d][b_local]
        const int rb = blockIdx.x - 128;   // 0..511
        const int b0 = rb << 3;
        const int bl = t >> 5;             // 0..7
        const int dg = t & 31;             // float4 slot within row
        const float* zp = z + (((size_t)b0 + bl) << 7) + (dg << 2);
        float s10 = 0.f, s11 = 0.f, s12 = 0.f, s13 = 0.f;
        float s20 = 0.f, s21 = 0.f, s22 = 0.f, s23 = 0.f;
        #pragma unroll
        for (int mc = 0; mc < 16; ++mc) {
            float4 v = *(const float4*)(zp + (size_t)mc * 524288);
            s10 += v.x; s20 = fmaf(v.x, v.x, s20);
            s11 += v.y; s21 = fmaf(v.y, v.y, s21);
            s12 += v.z; s22 = fmaf(v.z, v.z, s22);
            s13 += v.w; s23 = fmaf(v.w, v.w, s23);
        }
        const int d0 = dg << 2;
        tr[d0    ][bl] = make_float2(s10 * 0.0625f, s20 * 0.0625f);
        tr[d0 + 1][bl] = make_float2(s11 * 0.0625f, s21 * 0.0625f);
        tr[d0 + 2][bl] = make_float2(s12 * 0.0625f, s22 * 0.0625f);
        tr[d0 + 3][bl] = make_float2(s13 * 0.0625f, s23 * 0.0625f);
        __syncthreads();
        // write xy_t[d][b0..b0+7]: thread t<128 copies its d-row (64 B)
        if (t < 128) {
            const float4* rp = (const float4*)&tr[t][0];
            float4* gp = (float4*)xyt + ((size_t)t << 11) + (b0 >> 1);
            gp[0] = rp[0]; gp[1] = rp[1]; gp[2] = rp[2]; gp[3] = rp[3];
        }
    }
}

// 512 blocks x 256 t. Tile 256 b x 4 d. Wave w owns d = d0+w (uniform);
// lane l holds coefficients for k in {4l..4l+3} in 12 VGPRs, broadcast via
// v_readlane (pure VALU, zero LDS / zero memory in the k-loop). Lane owns
// 4 b values; xy_t reads are perfect 512 B wave-segments.
__global__ __launch_bounds__(256) void lse_kernel(
    const float* __restrict__ Ac, const float* __restrict__ Bc,
    const float* __restrict__ Cc, const float2* __restrict__ xyt,
    float* __restrict__ out)
{
    __shared__ float res[4][260];

    const int t  = threadIdx.x;
    const int l  = t & 63;
    const int wv = t >> 6;
    const int b0 = (int)blockIdx.x << 8;                 // 16 b-chunks
    const int d0 = (int)blockIdx.y << 2;                 // 32 d-chunks
    const int d  = __builtin_amdgcn_readfirstlane(d0 + wv);

    const int ci = (d << 8) + (l << 2);
    const float4 cA = *(const float4*)&Ac[ci];
    const float4 cB = *(const float4*)&Bc[ci];
    const float4 cC = *(const float4*)&Cc[ci];

    const float2* xp = xyt + ((size_t)d << 12) + b0 + l;
    float x0, x1, x2, x3, y0, y1, y2, y3;
    { float2 v = xp[0];   x0 = v.x; y0 = v.y; }
    { float2 v = xp[64];  x1 = v.x; y1 = v.y; }
    { float2 v = xp[128]; x2 = v.x; y2 = v.y; }
    { float2 v = xp[192]; x3 = v.x; y3 = v.y; }

    float a0 = 0.f, a1 = 0.f, a2 = 0.f, a3 = 0.f;

    #define RL(v) __int_as_float(__builtin_amdgcn_readlane(__float_as_int(v), k0))
    #define BODY(F)                                                          \
    {                                                                        \
        float sa = RL(cA.F), sb = RL(cB.F), sc = RL(cC.F);                   \
        a0 += __builtin_amdgcn_exp2f(fmaf(sc, y0, fmaf(sb, x0, sa)));        \
        a1 += __builtin_amdgcn_exp2f(fmaf(sc, y1, fmaf(sb, x1, sa)));        \
        a2 += __builtin_amdgcn_exp2f(fmaf(sc, y2, fmaf(sb, x2, sa)));        \
        a3 += __builtin_amdgcn_exp2f(fmaf(sc, y3, fmaf(sb, x3, sa)));        \
    }
    #pragma unroll 4
    for (int k0 = 0; k0 < 64; ++k0) {
        BODY(x) BODY(y) BODY(z) BODY(w)
    }
    #undef BODY
    #undef RL

    res[wv][l]       = LN2_F * __builtin_amdgcn_logf(a0);
    res[wv][l +  64] = LN2_F * __builtin_amdgcn_logf(a1);
    res[wv][l + 128] = LN2_F * __builtin_amdgcn_logf(a2);
    res[wv][l + 192] = LN2_F * __builtin_amdgcn_logf(a3);
    __syncthreads();

    // out[b][d0..d0+3] as one float4 per b; L2 merges across d-chunk blocks
    // (same bc -> same XCD since linear id % 8 == bc % 8).
    float4 o = make_float4(res[0][t], res[1][t], res[2][t], res[3][t]);
    *(float4*)&out[((size_t)(b0 + t) << 7) + d0] = o;
}

extern "C" void kernel_launch(void* const* d_in, const int* in_sizes, int n_in,
                              void* d_out, int out_size, void* d_ws, size_t ws_size,
                              hipStream_t stream) {
    const float* z        = (const float*)d_in[0];
    const float* means    = (const float*)d_in[1];
    const float* log_vars = (const float*)d_in[2];
    const float* w        = (const float*)d_in[3];
    float* out = (float*)d_out;

    char* ws = (char*)d_ws;
    float*  Ac  = (float*)(ws);
    float*  Bc  = (float*)(ws + (128 << 10));
    float*  Cc  = (float*)(ws + (256 << 10));
    float2* xyt = (float2*)(ws + (384 << 10));

    prep_kernel<<<640, 256, 0, stream>>>(z, means, log_vars, w, Ac, Bc, Cc, xyt);
    lse_kernel<<<dim3(16, 32), 256, 0, stream>>>(Ac, Bc, Cc, xyt, out);
}